// Round 2
// baseline (2983.059 us; speedup 1.0000x reference)
//
#include <hip/hip_runtime.h>
#include <hip/hip_bf16.h>

typedef __bf16 bf16x8_t __attribute__((ext_vector_type(8)));
typedef __bf16 bf16x4_t __attribute__((ext_vector_type(4)));
typedef float f32x4_t __attribute__((ext_vector_type(4)));

#define M_TX 100000
#define FDIM 256
#define HDIM 256
#define KTOT 512

// ---------------- init: logits = b_out, summed = 0, cnt = 0 ----------------
__global__ __launch_bounds__(256) void initk(float* __restrict__ out,
                                             float* __restrict__ cnt,
                                             const float* __restrict__ b_out) {
    const int n4 = (M_TX + M_TX * HDIM) / 4;  // 6,425,000 float4s cover all of d_out
    const int c4 = M_TX / 4;                  // 25,000 float4s of logits / cnt
    float b0 = b_out[0];
    f32x4_t zero = {0.f, 0.f, 0.f, 0.f};
    f32x4_t bv = {b0, b0, b0, b0};
    int stride = gridDim.x * blockDim.x;
    for (int i = blockIdx.x * blockDim.x + threadIdx.x; i < n4; i += stride) {
        ((f32x4_t*)out)[i] = (i < c4) ? bv : zero;
        if (i < c4) ((f32x4_t*)cnt)[i] = zero;
    }
}

// ---------------- transpose W_l|W_r (f32 [k][n]) -> WT bf16 [n][k0..511] ----
__global__ __launch_bounds__(256) void transw(const float* __restrict__ Wl,
                                              const float* __restrict__ Wr,
                                              __bf16* __restrict__ WT) {
    int t = blockIdx.x * 256 + threadIdx.x;   // 65536 threads: one (k,n) each
    if (t >= FDIM * HDIM) return;
    int k = t >> 8;
    int n = t & 255;
    WT[n * KTOT + k]        = (__bf16)Wl[k * HDIM + n];
    WT[n * KTOT + 256 + k]  = (__bf16)Wr[k * HDIM + n];
}

// ---------------- edge aggregation: one wave per edge ----------------------
__global__ __launch_bounds__(256) void aggk(const float* __restrict__ x_acc,
                                            const int* __restrict__ esrc,
                                            const int* __restrict__ edst,
                                            float* __restrict__ summed,
                                            float* __restrict__ cnt, int E) {
    int gid = blockIdx.x * 256 + threadIdx.x;
    int e = gid >> 6;
    if (e >= E) return;
    int lane = gid & 63;
    int s = esrc[e];
    int d = edst[e];
    const f32x4_t v = *(const f32x4_t*)(x_acc + (long)s * FDIM + lane * 4);
    float* p = summed + (long)d * FDIM + lane * 4;
    unsafeAtomicAdd(p + 0, v.x);
    unsafeAtomicAdd(p + 1, v.y);
    unsafeAtomicAdd(p + 2, v.z);
    unsafeAtomicAdd(p + 3, v.w);
    if (lane == 0) unsafeAtomicAdd(cnt + d, 1.0f);
}

// ---------------- fused GEMM: h = mean@W_l + x_tx@W_r + b_l; relu; logits ---
// A (M x 512) = [mean | x_tx] built on the fly (bf16), B = WT (bf16, [n][k]).
// Each block: 128 rows x full N=256.  8 waves = 2 (M) x 4 (N), 64x64 per wave.
__global__ __launch_bounds__(512) void gemmk(const float* __restrict__ x_tx,
                                             const float* __restrict__ summed,
                                             const float* __restrict__ cnt,
                                             const __bf16* __restrict__ WT,
                                             const float* __restrict__ b_l,
                                             const float* __restrict__ W_out,
                                             float* __restrict__ tx_out,
                                             float* __restrict__ logits) {
    __shared__ __bf16 As[128][72];   // [row][k], +8 pad
    __shared__ __bf16 Bs[256][72];   // [col][k], +8 pad

    const int m0 = blockIdx.x * 128;
    const int tid = threadIdx.x;
    const int wid = tid >> 6;
    const int lane = tid & 63;
    const int wm = wid >> 2;         // 0..1
    const int wn = wid & 3;          // 0..3
    const int lc = lane & 15;
    const int lr = lane >> 4;

    f32x4_t acc[4][4];
#pragma unroll
    for (int i = 0; i < 4; ++i)
#pragma unroll
        for (int j = 0; j < 4; ++j) acc[i][j] = (f32x4_t){0.f, 0.f, 0.f, 0.f};

    // A staging map: row = tid>>2 (0..127), quarter = tid&3 (16 cols each)
    const int ar = tid >> 2;
    const int acq = tid & 3;
    const int arm = m0 + ar;
    const bool arow_ok = arm < M_TX;
    float invc;
    {
        float c = cnt[arow_ok ? arm : (M_TX - 1)];
        invc = 1.0f / fmaxf(c, 1.0f);
    }

    for (int kc = 0; kc < 8; ++kc) {
        __syncthreads();  // previous compute done before overwriting LDS
        // ---- stage A tile (128 x 64 bf16) ----
        {
            const bool first = kc < 4;
            const int kb = (kc & 3) * 64;
            const float sc = first ? invc : 1.0f;
            const float* base = first ? (summed + (long)arm * FDIM + kb)
                                      : (x_tx + (long)arm * FDIM + kb);
#pragma unroll
            for (int c4 = 0; c4 < 4; ++c4) {
                int kk = acq * 16 + c4 * 4;
                f32x4_t v = {0.f, 0.f, 0.f, 0.f};
                if (arow_ok) v = *(const f32x4_t*)(base + kk);
                bf16x4_t w;
                w[0] = (__bf16)(v.x * sc);
                w[1] = (__bf16)(v.y * sc);
                w[2] = (__bf16)(v.z * sc);
                w[3] = (__bf16)(v.w * sc);
                *(bf16x4_t*)(&As[ar][kk]) = w;
            }
        }
        // ---- stage B tile (256 x 64 bf16) from WT ----
#pragma unroll
        for (int i = 0; i < 4; ++i) {
            int t2 = tid + i * 512;
            int n = t2 >> 3;
            int c = t2 & 7;
            bf16x8_t v = *(const bf16x8_t*)(WT + n * KTOT + kc * 64 + c * 8);
            *(bf16x8_t*)(&Bs[n][c * 8]) = v;
        }
        __syncthreads();
        // ---- MFMA ----
        const int kfr = lr * 8;
#pragma unroll
        for (int kk = 0; kk < 2; ++kk) {
            bf16x8_t af[4], bfr[4];
#pragma unroll
            for (int f = 0; f < 4; ++f) {
                af[f] = *(const bf16x8_t*)(&As[wm * 64 + f * 16 + lc][kk * 32 + kfr]);
                bfr[f] = *(const bf16x8_t*)(&Bs[wn * 64 + f * 16 + lc][kk * 32 + kfr]);
            }
#pragma unroll
            for (int fm = 0; fm < 4; ++fm)
#pragma unroll
                for (int fn = 0; fn < 4; ++fn)
                    acc[fm][fn] = __builtin_amdgcn_mfma_f32_16x16x32_bf16(
                        af[fm], bfr[fn], acc[fm][fn], 0, 0, 0);
        }
    }

    // ---- epilogue: bias, relu, store tx_x, fused logits ----
    float wout[4], bl[4];
#pragma unroll
    for (int fn = 0; fn < 4; ++fn) {
        int col = wn * 64 + fn * 16 + lc;
        wout[fn] = W_out[col];
        bl[fn] = b_l[col];
    }
#pragma unroll
    for (int fm = 0; fm < 4; ++fm) {
        float part[4] = {0.f, 0.f, 0.f, 0.f};
#pragma unroll
        for (int fn = 0; fn < 4; ++fn) {
            int col = wn * 64 + fn * 16 + lc;
#pragma unroll
            for (int r = 0; r < 4; ++r) {
                int row = m0 + wm * 64 + fm * 16 + lr * 4 + r;
                float h = acc[fm][fn][r] + bl[fn];
                h = fmaxf(h, 0.0f);
                if (row < M_TX) tx_out[(long)row * HDIM + col] = h;
                part[r] += h * wout[fn];
            }
        }
#pragma unroll
        for (int r = 0; r < 4; ++r) {
            float p = part[r];
            p += __shfl_xor(p, 1);
            p += __shfl_xor(p, 2);
            p += __shfl_xor(p, 4);
            p += __shfl_xor(p, 8);
            int row = m0 + wm * 64 + fm * 16 + lr * 4 + r;
            if (lc == 0 && row < M_TX) unsafeAtomicAdd(logits + row, p);
        }
    }
}

extern "C" void kernel_launch(void* const* d_in, const int* in_sizes, int n_in,
                              void* d_out, int out_size, void* d_ws, size_t ws_size,
                              hipStream_t stream) {
    const float* x_tx  = (const float*)d_in[0];
    const float* x_acc = (const float*)d_in[1];
    const int* e_src   = (const int*)d_in[2];
    const int* e_dst   = (const int*)d_in[3];
    const float* W_l   = (const float*)d_in[6];
    const float* b_l   = (const float*)d_in[7];
    const float* W_r   = (const float*)d_in[8];
    const float* W_out = (const float*)d_in[12];
    const float* b_out = (const float*)d_in[13];

    float* out = (float*)d_out;
    float* logits = out;
    float* summed = out + M_TX;                    // reuse tx_x region as f32 accumulator

    __bf16* WT = (__bf16*)d_ws;                    // 256 x 512 bf16 = 256 KB
    float* cnt = (float*)((char*)d_ws + (size_t)HDIM * KTOT * sizeof(__bf16));

    const int E = in_sizes[2];

    hipLaunchKernelGGL(initk, dim3(2048), dim3(256), 0, stream, out, cnt, b_out);
    hipLaunchKernelGGL(transw, dim3((FDIM * HDIM + 255) / 256), dim3(256), 0, stream,
                       W_l, W_r, WT);
    hipLaunchKernelGGL(aggk, dim3((E + 3) / 4), dim3(256), 0, stream,
                       x_acc, e_src, e_dst, summed, cnt, E);
    hipLaunchKernelGGL(gemmk, dim3((M_TX + 127) / 128), dim3(512), 0, stream,
                       x_tx, summed, cnt, WT, b_l, W_out, out + M_TX, logits);
}

// Round 6
// 629.041 us; speedup vs baseline: 4.7422x; 4.7422x over previous
//
#include <hip/hip_runtime.h>
#include <hip/hip_bf16.h>

typedef __bf16 bf16x8_t __attribute__((ext_vector_type(8)));
typedef __bf16 bf16x4_t __attribute__((ext_vector_type(4)));
typedef float f32x4_t __attribute__((ext_vector_type(4)));

#define M_TX 100000
#define N_AC 50000
#define FDIM 256
#define HDIM 256
#define KTOT 512

// ---- init: logits = b_out, hist = 0, fill = 0 (no 102MB summed memset) ----
__global__ __launch_bounds__(256) void initk2(float* __restrict__ logits,
                                              int* __restrict__ hist,
                                              int* __restrict__ fill,
                                              const float* __restrict__ b_out) {
    int i = blockIdx.x * 256 + threadIdx.x;
    if (i < M_TX) {
        logits[i] = b_out[0];
        hist[i] = 0;
        fill[i] = 0;
    }
}

// ---- transpose W_l|W_r (f32 [k][n]) -> WT bf16 [n][k0..511] ----
__global__ __launch_bounds__(256) void transw(const float* __restrict__ Wl,
                                              const float* __restrict__ Wr,
                                              __bf16* __restrict__ WT) {
    int t = blockIdx.x * 256 + threadIdx.x;
    if (t >= FDIM * HDIM) return;
    int k = t >> 8;
    int n = t & 255;
    WT[n * KTOT + k]        = (__bf16)Wl[k * HDIM + n];
    WT[n * KTOT + 256 + k]  = (__bf16)Wr[k * HDIM + n];
}

// ---- histogram of dst degree (L2-resident int atomics) ----
__global__ __launch_bounds__(256) void histk(const int* __restrict__ edst,
                                             int* __restrict__ hist, int E) {
    int e = blockIdx.x * 256 + threadIdx.x;
    if (e >= E) return;
    atomicAdd(&hist[edst[e]], 1);
}

// ---- single-block segmented exclusive scan: hist[0..M) -> row_start[0..M] ----
__global__ __launch_bounds__(1024) void scank(const int* __restrict__ hist,
                                              int* __restrict__ row_start) {
    __shared__ int sums[1024];
    const int t = threadIdx.x;
    const int SEG = (M_TX + 1023) / 1024;  // 98
    int lo = t * SEG;
    int hi = lo + SEG; if (hi > M_TX) hi = M_TX;
    if (lo > M_TX) lo = M_TX;
    int s = 0;
    for (int i = lo; i < hi; ++i) s += hist[i];
    sums[t] = s;
    __syncthreads();
    // Hillis-Steele inclusive scan over 1024 partials
    for (int off = 1; off < 1024; off <<= 1) {
        int v = (t >= off) ? sums[t - off] : 0;
        __syncthreads();
        sums[t] += v;
        __syncthreads();
    }
    int running = (t == 0) ? 0 : sums[t - 1];
    for (int i = lo; i < hi; ++i) {
        row_start[i] = running;
        running += hist[i];
    }
    if (t == 1023) row_start[M_TX] = sums[1023];
}

// ---- scatter edges into CSR order (bucket sort by dst) ----
__global__ __launch_bounds__(256) void scatterk(const int* __restrict__ esrc,
                                                const int* __restrict__ edst,
                                                const int* __restrict__ row_start,
                                                int* __restrict__ fill,
                                                int* __restrict__ sorted_src, int E) {
    int e = blockIdx.x * 256 + threadIdx.x;
    if (e >= E) return;
    int d = edst[e];
    int pos = row_start[d] + atomicAdd(&fill[d], 1);
    sorted_src[pos] = esrc[e];
}

// ---- gather-sum: one wave per dst row, zero atomics ----
__global__ __launch_bounds__(256) void gatherk(const float* __restrict__ x_acc,
                                               const int* __restrict__ sorted_src,
                                               const int* __restrict__ row_start,
                                               float* __restrict__ summed) {
    int gw = (blockIdx.x * 256 + threadIdx.x) >> 6;  // global wave id = dst row
    if (gw >= M_TX) return;
    int lane = threadIdx.x & 63;
    int start = row_start[gw];
    int end = row_start[gw + 1];
    f32x4_t acc = {0.f, 0.f, 0.f, 0.f};
    for (int base = start; base < end; base += 64) {
        int n = end - base; if (n > 64) n = 64;
        int s = 0;
        if (base + lane < end) s = sorted_src[base + lane];
        for (int j = 0; j < n; ++j) {
            int sj = __shfl(s, j);
            const f32x4_t v = *(const f32x4_t*)(x_acc + (long)sj * FDIM + lane * 4);
            acc.x += v.x; acc.y += v.y; acc.z += v.z; acc.w += v.w;
        }
    }
    *(f32x4_t*)(summed + (long)gw * FDIM + lane * 4) = acc;
}

// ---- fused GEMM: h = mean@W_l + x_tx@W_r + b_l; relu; tx_x + logits ----
__global__ __launch_bounds__(512) void gemmk(const float* __restrict__ x_tx,
                                             const float* __restrict__ summed,
                                             const int* __restrict__ row_start,
                                             const __bf16* __restrict__ WT,
                                             const float* __restrict__ b_l,
                                             const float* __restrict__ W_out,
                                             float* __restrict__ tx_out,
                                             float* __restrict__ logits) {
    __shared__ __bf16 As[128][72];   // [row][k], +8 pad
    __shared__ __bf16 Bs[256][72];   // [col][k], +8 pad

    const int m0 = blockIdx.x * 128;
    const int tid = threadIdx.x;
    const int wid = tid >> 6;
    const int lane = tid & 63;
    const int wm = wid >> 2;         // 0..1
    const int wn = wid & 3;          // 0..3
    const int lc = lane & 15;
    const int lr = lane >> 4;

    f32x4_t acc[4][4];
#pragma unroll
    for (int i = 0; i < 4; ++i)
#pragma unroll
        for (int j = 0; j < 4; ++j) acc[i][j] = (f32x4_t){0.f, 0.f, 0.f, 0.f};

    const int ar = tid >> 2;
    const int acq = tid & 3;
    const int arm = m0 + ar;
    const bool arow_ok = arm < M_TX;
    float invc;
    {
        int idx = arow_ok ? arm : (M_TX - 1);
        int c = row_start[idx + 1] - row_start[idx];
        invc = 1.0f / fmaxf((float)c, 1.0f);
    }

    for (int kc = 0; kc < 8; ++kc) {
        __syncthreads();
        // ---- stage A tile (128 x 64 bf16) ----
        {
            const bool first = kc < 4;
            const int kb = (kc & 3) * 64;
            const float sc = first ? invc : 1.0f;
            const float* base = first ? (summed + (long)arm * FDIM + kb)
                                      : (x_tx + (long)arm * FDIM + kb);
#pragma unroll
            for (int c4 = 0; c4 < 4; ++c4) {
                int kk = acq * 16 + c4 * 4;
                f32x4_t v = {0.f, 0.f, 0.f, 0.f};
                if (arow_ok) v = *(const f32x4_t*)(base + kk);
                bf16x4_t w;
                w[0] = (__bf16)(v.x * sc);
                w[1] = (__bf16)(v.y * sc);
                w[2] = (__bf16)(v.z * sc);
                w[3] = (__bf16)(v.w * sc);
                *(bf16x4_t*)(&As[ar][kk]) = w;
            }
        }
        // ---- stage B tile (256 x 64 bf16) from WT ----
#pragma unroll
        for (int i = 0; i < 4; ++i) {
            int t2 = tid + i * 512;
            int n = t2 >> 3;
            int c = t2 & 7;
            bf16x8_t v = *(const bf16x8_t*)(WT + n * KTOT + kc * 64 + c * 8);
            *(bf16x8_t*)(&Bs[n][c * 8]) = v;
        }
        __syncthreads();
        // ---- MFMA ----
        const int kfr = lr * 8;
#pragma unroll
        for (int kk = 0; kk < 2; ++kk) {
            bf16x8_t af[4], bfr[4];
#pragma unroll
            for (int f = 0; f < 4; ++f) {
                af[f] = *(const bf16x8_t*)(&As[wm * 64 + f * 16 + lc][kk * 32 + kfr]);
                bfr[f] = *(const bf16x8_t*)(&Bs[wn * 64 + f * 16 + lc][kk * 32 + kfr]);
            }
#pragma unroll
            for (int fm = 0; fm < 4; ++fm)
#pragma unroll
                for (int fn = 0; fn < 4; ++fn)
                    acc[fm][fn] = __builtin_amdgcn_mfma_f32_16x16x32_bf16(
                        af[fm], bfr[fn], acc[fm][fn], 0, 0, 0);
        }
    }

    // ---- epilogue: bias, relu, store tx_x, fused logits ----
    float wout[4], bl[4];
#pragma unroll
    for (int fn = 0; fn < 4; ++fn) {
        int col = wn * 64 + fn * 16 + lc;
        wout[fn] = W_out[col];
        bl[fn] = b_l[col];
    }
#pragma unroll
    for (int fm = 0; fm < 4; ++fm) {
        float part[4] = {0.f, 0.f, 0.f, 0.f};
#pragma unroll
        for (int fn = 0; fn < 4; ++fn) {
            int col = wn * 64 + fn * 16 + lc;
#pragma unroll
            for (int r = 0; r < 4; ++r) {
                int row = m0 + wm * 64 + fm * 16 + lr * 4 + r;
                float h = acc[fm][fn][r] + bl[fn];
                h = fmaxf(h, 0.0f);
                if (row < M_TX) tx_out[(long)row * HDIM + col] = h;
                part[r] += h * wout[fn];
            }
        }
#pragma unroll
        for (int r = 0; r < 4; ++r) {
            float p = part[r];
            p += __shfl_xor(p, 1);
            p += __shfl_xor(p, 2);
            p += __shfl_xor(p, 4);
            p += __shfl_xor(p, 8);
            int row = m0 + wm * 64 + fm * 16 + lr * 4 + r;
            if (lc == 0 && row < M_TX) unsafeAtomicAdd(logits + row, p);
        }
    }
}

extern "C" void kernel_launch(void* const* d_in, const int* in_sizes, int n_in,
                              void* d_out, int out_size, void* d_ws, size_t ws_size,
                              hipStream_t stream) {
    const float* x_tx  = (const float*)d_in[0];
    const float* x_acc = (const float*)d_in[1];
    const int* e_src   = (const int*)d_in[2];
    const int* e_dst   = (const int*)d_in[3];
    const float* W_l   = (const float*)d_in[6];
    const float* b_l   = (const float*)d_in[7];
    const float* W_r   = (const float*)d_in[8];
    const float* W_out = (const float*)d_in[12];
    const float* b_out = (const float*)d_in[13];

    float* out = (float*)d_out;
    float* logits = out;
    float* summed = out + M_TX;   // f32 accumulator lives in tx_x region (row-exact overwrite later)

    // workspace layout (all offsets verified non-overlapping, ~4.8 MB total)
    char* ws = (char*)d_ws;
    __bf16* WT       = (__bf16*)ws;                                   // 256 KB
    int* row_start   = (int*)(ws + 256 * 1024);                       // 400,004 B
    int* fill        = (int*)(ws + 256 * 1024 + 400 * 1024 + 1024);   // 400 KB
    int* sorted_src  = (int*)(ws + 256 * 1024 + 800 * 1024 + 2048);   // 3.2 MB
    int* histp       = (int*)(ws + 256 * 1024 + 800 * 1024 + 2048 + 3200 * 1024 + 1024);

    const int E = in_sizes[2];

    hipLaunchKernelGGL(initk2, dim3((M_TX + 255) / 256), dim3(256), 0, stream,
                       logits, histp, fill, b_out);
    hipLaunchKernelGGL(transw, dim3((FDIM * HDIM + 255) / 256), dim3(256), 0, stream,
                       W_l, W_r, WT);
    hipLaunchKernelGGL(histk, dim3((E + 255) / 256), dim3(256), 0, stream,
                       e_dst, histp, E);
    hipLaunchKernelGGL(scank, dim3(1), dim3(1024), 0, stream, histp, row_start);
    hipLaunchKernelGGL(scatterk, dim3((E + 255) / 256), dim3(256), 0, stream,
                       e_src, e_dst, row_start, fill, sorted_src, E);
    hipLaunchKernelGGL(gatherk, dim3(M_TX / 4), dim3(256), 0, stream,
                       x_acc, sorted_src, row_start, summed);
    hipLaunchKernelGGL(gemmk, dim3((M_TX + 127) / 128), dim3(512), 0, stream,
                       x_tx, summed, row_start, WT, b_l, W_out, out + M_TX, logits);
}

// Round 8
// 478.348 us; speedup vs baseline: 6.2362x; 1.3150x over previous
//
#include <hip/hip_runtime.h>
#include <hip/hip_bf16.h>

typedef __bf16 bf16x8_t __attribute__((ext_vector_type(8)));
typedef __bf16 bf16x4_t __attribute__((ext_vector_type(4)));
typedef float f32x4_t __attribute__((ext_vector_type(4)));

#define M_TX 100000
#define N_AC 50000
#define FDIM 256
#define HDIM 256
#define KTOT 512
#define SCAN_NBLK ((M_TX + 1023) / 1024)   // 98

// ---- init: logits = b_out, hist = 0, fill = 0 (no 102MB summed memset) ----
__global__ __launch_bounds__(256) void initk2(float* __restrict__ logits,
                                              int* __restrict__ hist,
                                              int* __restrict__ fill,
                                              const float* __restrict__ b_out) {
    int i = blockIdx.x * 256 + threadIdx.x;
    if (i < M_TX) {
        logits[i] = b_out[0];
        hist[i] = 0;
        fill[i] = 0;
    }
}

// ---- transpose W_l|W_r (f32 [k][n]) -> WT bf16 [n][k0..511] ----
__global__ __launch_bounds__(256) void transw(const float* __restrict__ Wl,
                                              const float* __restrict__ Wr,
                                              __bf16* __restrict__ WT) {
    int t = blockIdx.x * 256 + threadIdx.x;
    if (t >= FDIM * HDIM) return;
    int k = t >> 8;
    int n = t & 255;
    WT[n * KTOT + k]        = (__bf16)Wl[k * HDIM + n];
    WT[n * KTOT + 256 + k]  = (__bf16)Wr[k * HDIM + n];
}

// ---- histogram of dst degree (L2-resident int atomics) ----
__global__ __launch_bounds__(256) void histk(const int* __restrict__ edst,
                                             int* __restrict__ hist, int E) {
    int e = blockIdx.x * 256 + threadIdx.x;
    if (e >= E) return;
    atomicAdd(&hist[edst[e]], 1);
}

// ---- scan pass 1: per-block local exclusive scan + block totals ----
__global__ __launch_bounds__(1024) void scan1k(const int* __restrict__ hist,
                                               int* __restrict__ row_start,
                                               int* __restrict__ partials) {
    __shared__ int tmp[1024];
    const int b = blockIdx.x;
    const int t = threadIdx.x;
    const int i = b * 1024 + t;
    int v = (i < M_TX) ? hist[i] : 0;
    tmp[t] = v;
    __syncthreads();
    for (int off = 1; off < 1024; off <<= 1) {
        int u = (t >= off) ? tmp[t - off] : 0;
        __syncthreads();
        tmp[t] += u;
        __syncthreads();
    }
    if (i < M_TX) row_start[i] = tmp[t] - v;   // local exclusive
    if (t == 1023) partials[b] = tmp[1023];    // block total
}

// ---- scan pass 2: exclusive-scan the 98 block totals; write grand total ----
__global__ __launch_bounds__(128) void scan2k(int* __restrict__ partials,
                                              int* __restrict__ row_start) {
    __shared__ int tmp[128];
    const int t = threadIdx.x;
    int v = (t < SCAN_NBLK) ? partials[t] : 0;
    tmp[t] = v;
    __syncthreads();
    for (int off = 1; off < 128; off <<= 1) {
        int u = (t >= off) ? tmp[t - off] : 0;
        __syncthreads();
        tmp[t] += u;
        __syncthreads();
    }
    if (t < SCAN_NBLK) partials[t] = tmp[t] - v;   // exclusive block offset
    if (t == 127) row_start[M_TX] = tmp[127];      // = E
}

// ---- scan pass 3: add block offsets ----
__global__ __launch_bounds__(1024) void scan3k(int* __restrict__ row_start,
                                               const int* __restrict__ partials) {
    const int i = blockIdx.x * 1024 + threadIdx.x;
    if (i < M_TX) row_start[i] += partials[blockIdx.x];
}

// ---- scatter edges into CSR order (bucket sort by dst) ----
__global__ __launch_bounds__(256) void scatterk(const int* __restrict__ esrc,
                                                const int* __restrict__ edst,
                                                const int* __restrict__ row_start,
                                                int* __restrict__ fill,
                                                int* __restrict__ sorted_src, int E) {
    int e = blockIdx.x * 256 + threadIdx.x;
    if (e >= E) return;
    int d = edst[e];
    int pos = row_start[d] + atomicAdd(&fill[d], 1);
    sorted_src[pos] = esrc[e];
}

// ---- gather-sum: one wave per dst row, zero atomics ----
__global__ __launch_bounds__(256) void gatherk(const float* __restrict__ x_acc,
                                               const int* __restrict__ sorted_src,
                                               const int* __restrict__ row_start,
                                               float* __restrict__ summed) {
    int gw = (blockIdx.x * 256 + threadIdx.x) >> 6;  // global wave id = dst row
    if (gw >= M_TX) return;
    int lane = threadIdx.x & 63;
    int start = row_start[gw];
    int end = row_start[gw + 1];
    f32x4_t acc = {0.f, 0.f, 0.f, 0.f};
    for (int base = start; base < end; base += 64) {
        int n = end - base; if (n > 64) n = 64;
        int s = 0;
        if (base + lane < end) s = sorted_src[base + lane];
        for (int j = 0; j < n; ++j) {
            int sj = __shfl(s, j);
            const f32x4_t v = *(const f32x4_t*)(x_acc + (long)sj * FDIM + lane * 4);
            acc.x += v.x; acc.y += v.y; acc.z += v.z; acc.w += v.w;
        }
    }
    *(f32x4_t*)(summed + (long)gw * FDIM + lane * 4) = acc;
}

// ---- fused GEMM: h = mean@W_l + x_tx@W_r + b_l; relu; tx_x + logits ----
__global__ __launch_bounds__(512) void gemmk(const float* __restrict__ x_tx,
                                             const float* __restrict__ summed,
                                             const int* __restrict__ row_start,
                                             const __bf16* __restrict__ WT,
                                             const float* __restrict__ b_l,
                                             const float* __restrict__ W_out,
                                             float* __restrict__ tx_out,
                                             float* __restrict__ logits) {
    __shared__ __bf16 As[128][72];   // [row][k], +8 pad
    __shared__ __bf16 Bs[256][72];   // [col][k], +8 pad

    const int m0 = blockIdx.x * 128;
    const int tid = threadIdx.x;
    const int wid = tid >> 6;
    const int lane = tid & 63;
    const int wm = wid >> 2;         // 0..1
    const int wn = wid & 3;          // 0..3
    const int lc = lane & 15;
    const int lr = lane >> 4;

    f32x4_t acc[4][4];
#pragma unroll
    for (int i = 0; i < 4; ++i)
#pragma unroll
        for (int j = 0; j < 4; ++j) acc[i][j] = (f32x4_t){0.f, 0.f, 0.f, 0.f};

    const int ar = tid >> 2;
    const int acq = tid & 3;
    const int arm = m0 + ar;
    const bool arow_ok = arm < M_TX;
    float invc;
    {
        int idx = arow_ok ? arm : (M_TX - 1);
        int c = row_start[idx + 1] - row_start[idx];
        invc = 1.0f / fmaxf((float)c, 1.0f);
    }

    for (int kc = 0; kc < 8; ++kc) {
        __syncthreads();
        // ---- stage A tile (128 x 64 bf16) ----
        {
            const bool first = kc < 4;
            const int kb = (kc & 3) * 64;
            const float sc = first ? invc : 1.0f;
            const float* base = first ? (summed + (long)arm * FDIM + kb)
                                      : (x_tx + (long)arm * FDIM + kb);
#pragma unroll
            for (int c4 = 0; c4 < 4; ++c4) {
                int kk = acq * 16 + c4 * 4;
                f32x4_t v = {0.f, 0.f, 0.f, 0.f};
                if (arow_ok) v = *(const f32x4_t*)(base + kk);
                bf16x4_t w;
                w[0] = (__bf16)(v.x * sc);
                w[1] = (__bf16)(v.y * sc);
                w[2] = (__bf16)(v.z * sc);
                w[3] = (__bf16)(v.w * sc);
                *(bf16x4_t*)(&As[ar][kk]) = w;
            }
        }
        // ---- stage B tile (256 x 64 bf16) from WT ----
#pragma unroll
        for (int i = 0; i < 4; ++i) {
            int t2 = tid + i * 512;
            int n = t2 >> 3;
            int c = t2 & 7;
            bf16x8_t v = *(const bf16x8_t*)(WT + n * KTOT + kc * 64 + c * 8);
            *(bf16x8_t*)(&Bs[n][c * 8]) = v;
        }
        __syncthreads();
        // ---- MFMA ----
        const int kfr = lr * 8;
#pragma unroll
        for (int kk = 0; kk < 2; ++kk) {
            bf16x8_t af[4], bfr[4];
#pragma unroll
            for (int f = 0; f < 4; ++f) {
                af[f] = *(const bf16x8_t*)(&As[wm * 64 + f * 16 + lc][kk * 32 + kfr]);
                bfr[f] = *(const bf16x8_t*)(&Bs[wn * 64 + f * 16 + lc][kk * 32 + kfr]);
            }
#pragma unroll
            for (int fm = 0; fm < 4; ++fm)
#pragma unroll
                for (int fn = 0; fn < 4; ++fn)
                    acc[fm][fn] = __builtin_amdgcn_mfma_f32_16x16x32_bf16(
                        af[fm], bfr[fn], acc[fm][fn], 0, 0, 0);
        }
    }

    // ---- epilogue: bias, relu, store tx_x, fused logits ----
    float wout[4], bl[4];
#pragma unroll
    for (int fn = 0; fn < 4; ++fn) {
        int col = wn * 64 + fn * 16 + lc;
        wout[fn] = W_out[col];
        bl[fn] = b_l[col];
    }
#pragma unroll
    for (int fm = 0; fm < 4; ++fm) {
        float part[4] = {0.f, 0.f, 0.f, 0.f};
#pragma unroll
        for (int fn = 0; fn < 4; ++fn) {
            int col = wn * 64 + fn * 16 + lc;
#pragma unroll
            for (int r = 0; r < 4; ++r) {
                int row = m0 + wm * 64 + fm * 16 + lr * 4 + r;
                float h = acc[fm][fn][r] + bl[fn];
                h = fmaxf(h, 0.0f);
                if (row < M_TX) tx_out[(long)row * HDIM + col] = h;
                part[r] += h * wout[fn];
            }
        }
#pragma unroll
        for (int r = 0; r < 4; ++r) {
            float p = part[r];
            p += __shfl_xor(p, 1);
            p += __shfl_xor(p, 2);
            p += __shfl_xor(p, 4);
            p += __shfl_xor(p, 8);
            int row = m0 + wm * 64 + fm * 16 + lr * 4 + r;
            if (lc == 0 && row < M_TX) unsafeAtomicAdd(logits + row, p);
        }
    }
}

extern "C" void kernel_launch(void* const* d_in, const int* in_sizes, int n_in,
                              void* d_out, int out_size, void* d_ws, size_t ws_size,
                              hipStream_t stream) {
    const float* x_tx  = (const float*)d_in[0];
    const float* x_acc = (const float*)d_in[1];
    const int* e_src   = (const int*)d_in[2];
    const int* e_dst   = (const int*)d_in[3];
    const float* W_l   = (const float*)d_in[6];
    const float* b_l   = (const float*)d_in[7];
    const float* W_r   = (const float*)d_in[8];
    const float* W_out = (const float*)d_in[12];
    const float* b_out = (const float*)d_in[13];

    float* out = (float*)d_out;
    float* logits = out;
    float* summed = out + M_TX;   // f32 accumulator lives in tx_x region (row-exact overwrite later)

    // workspace layout (non-overlapping, ~4.8 MB total)
    char* ws = (char*)d_ws;
    __bf16* WT       = (__bf16*)ws;                                   // 256 KB
    int* row_start   = (int*)(ws + 256 * 1024);                       // 400,004 B
    int* fill        = (int*)(ws + 256 * 1024 + 400 * 1024 + 1024);   // 400 KB
    int* sorted_src  = (int*)(ws + 256 * 1024 + 800 * 1024 + 2048);   // 3.2 MB
    int* histp       = (int*)(ws + 256 * 1024 + 800 * 1024 + 2048 + 3200 * 1024 + 1024);
    int* partials    = (int*)(ws + 256 * 1024 + 800 * 1024 + 2048 + 3200 * 1024 + 1024
                              + 400 * 1024 + 1024);                   // 98 ints

    const int E = in_sizes[2];

    hipLaunchKernelGGL(initk2, dim3((M_TX + 255) / 256), dim3(256), 0, stream,
                       logits, histp, fill, b_out);
    hipLaunchKernelGGL(transw, dim3((FDIM * HDIM + 255) / 256), dim3(256), 0, stream,
                       W_l, W_r, WT);
    hipLaunchKernelGGL(histk, dim3((E + 255) / 256), dim3(256), 0, stream,
                       e_dst, histp, E);
    hipLaunchKernelGGL(scan1k, dim3(SCAN_NBLK), dim3(1024), 0, stream,
                       histp, row_start, partials);
    hipLaunchKernelGGL(scan2k, dim3(1), dim3(128), 0, stream, partials, row_start);
    hipLaunchKernelGGL(scan3k, dim3(SCAN_NBLK), dim3(1024), 0, stream,
                       row_start, partials);
    hipLaunchKernelGGL(scatterk, dim3((E + 255) / 256), dim3(256), 0, stream,
                       e_src, e_dst, row_start, fill, sorted_src, E);
    hipLaunchKernelGGL(gatherk, dim3(M_TX / 4), dim3(256), 0, stream,
                       x_acc, sorted_src, row_start, summed);
    hipLaunchKernelGGL(gemmk, dim3((M_TX + 127) / 128), dim3(512), 0, stream,
                       x_tx, summed, row_start, WT, b_l, W_out, out + M_TX, logits);
}

// Round 10
// 462.844 us; speedup vs baseline: 6.4451x; 1.0335x over previous
//
#include <hip/hip_runtime.h>
#include <hip/hip_bf16.h>

typedef __bf16 bf16x8_t __attribute__((ext_vector_type(8)));
typedef __bf16 bf16x4_t __attribute__((ext_vector_type(4)));
typedef float f32x4_t __attribute__((ext_vector_type(4)));

#define M_TX 100000
#define N_AC 50000
#define FDIM 256
#define HDIM 256
#define KTOT 512
#define SCAN_NBLK ((M_TX + 1023) / 1024)   // 98

__device__ inline bf16x8_t bzero8() {
    bf16x8_t v;
#pragma unroll
    for (int z = 0; z < 8; ++z) v[z] = (__bf16)0.f;
    return v;
}

// ---- init: logits = b_out, hist = 0, fill = 0 ----
__global__ __launch_bounds__(256) void initk2(float* __restrict__ logits,
                                              int* __restrict__ hist,
                                              int* __restrict__ fill,
                                              const float* __restrict__ b_out) {
    int i = blockIdx.x * 256 + threadIdx.x;
    if (i < M_TX) {
        logits[i] = b_out[0];
        hist[i] = 0;
        fill[i] = 0;
    }
}

// ---- transpose W_l|W_r (f32 [k][n]) -> WT bf16 [n][k0..511] ----
__global__ __launch_bounds__(256) void transw(const float* __restrict__ Wl,
                                              const float* __restrict__ Wr,
                                              __bf16* __restrict__ WT) {
    int t = blockIdx.x * 256 + threadIdx.x;
    if (t >= FDIM * HDIM) return;
    int k = t >> 8;
    int n = t & 255;
    WT[n * KTOT + k]        = (__bf16)Wl[k * HDIM + n];
    WT[n * KTOT + 256 + k]  = (__bf16)Wr[k * HDIM + n];
}

// ---- f32 -> bf16 bulk convert (vectorized, grid-stride) ----
__global__ __launch_bounds__(256) void cvtk(const float* __restrict__ src,
                                            __bf16* __restrict__ dst, int n4) {
    int stride = gridDim.x * 256;
    for (int i = blockIdx.x * 256 + threadIdx.x; i < n4; i += stride) {
        f32x4_t v = ((const f32x4_t*)src)[i];
        bf16x4_t w;
        w[0] = (__bf16)v.x; w[1] = (__bf16)v.y;
        w[2] = (__bf16)v.z; w[3] = (__bf16)v.w;
        ((bf16x4_t*)dst)[i] = w;
    }
}

// ---- histogram of dst degree ----
__global__ __launch_bounds__(256) void histk(const int* __restrict__ edst,
                                             int* __restrict__ hist, int E) {
    int e = blockIdx.x * 256 + threadIdx.x;
    if (e >= E) return;
    atomicAdd(&hist[edst[e]], 1);
}

// ---- scan pass 1: per-block local exclusive scan + block totals ----
__global__ __launch_bounds__(1024) void scan1k(const int* __restrict__ hist,
                                               int* __restrict__ row_start,
                                               int* __restrict__ partials) {
    __shared__ int tmp[1024];
    const int b = blockIdx.x;
    const int t = threadIdx.x;
    const int i = b * 1024 + t;
    int v = (i < M_TX) ? hist[i] : 0;
    tmp[t] = v;
    __syncthreads();
    for (int off = 1; off < 1024; off <<= 1) {
        int u = (t >= off) ? tmp[t - off] : 0;
        __syncthreads();
        tmp[t] += u;
        __syncthreads();
    }
    if (i < M_TX) row_start[i] = tmp[t] - v;
    if (t == 1023) partials[b] = tmp[1023];
}

// ---- scan pass 2: exclusive-scan block totals; write grand total ----
__global__ __launch_bounds__(128) void scan2k(int* __restrict__ partials,
                                              int* __restrict__ row_start) {
    __shared__ int tmp[128];
    const int t = threadIdx.x;
    int v = (t < SCAN_NBLK) ? partials[t] : 0;
    tmp[t] = v;
    __syncthreads();
    for (int off = 1; off < 128; off <<= 1) {
        int u = (t >= off) ? tmp[t - off] : 0;
        __syncthreads();
        tmp[t] += u;
        __syncthreads();
    }
    if (t < SCAN_NBLK) partials[t] = tmp[t] - v;
    if (t == 127) row_start[M_TX] = tmp[127];
}

// ---- scan pass 3: add block offsets ----
__global__ __launch_bounds__(1024) void scan3k(int* __restrict__ row_start,
                                               const int* __restrict__ partials) {
    const int i = blockIdx.x * 1024 + threadIdx.x;
    if (i < M_TX) row_start[i] += partials[blockIdx.x];
}

// ---- scatter edges into CSR order ----
__global__ __launch_bounds__(256) void scatterk(const int* __restrict__ esrc,
                                                const int* __restrict__ edst,
                                                const int* __restrict__ row_start,
                                                int* __restrict__ fill,
                                                int* __restrict__ sorted_src, int E) {
    int e = blockIdx.x * 256 + threadIdx.x;
    if (e >= E) return;
    int d = edst[e];
    int pos = row_start[d] + atomicAdd(&fill[d], 1);
    sorted_src[pos] = esrc[e];
}

// ---- gather-sum: one wave per dst row. Optional bf16 input / bf16 mean output.
__global__ __launch_bounds__(256) void gatherk(const float* __restrict__ x_acc,
                                               const __bf16* __restrict__ xab,
                                               const int* __restrict__ sorted_src,
                                               const int* __restrict__ row_start,
                                               float* __restrict__ summed,
                                               __bf16* __restrict__ meanb) {
    int gw = (blockIdx.x * 256 + threadIdx.x) >> 6;
    if (gw >= M_TX) return;
    int lane = threadIdx.x & 63;
    int start = row_start[gw];
    int end = row_start[gw + 1];
    f32x4_t acc = {0.f, 0.f, 0.f, 0.f};
    if (xab) {
        for (int base = start; base < end; base += 64) {
            int n = end - base; if (n > 64) n = 64;
            int s = 0;
            if (base + lane < end) s = sorted_src[base + lane];
            for (int j = 0; j < n; ++j) {
                int sj = __shfl(s, j);
                const bf16x4_t v = *(const bf16x4_t*)(xab + (long)sj * FDIM + lane * 4);
                acc.x += (float)v[0]; acc.y += (float)v[1];
                acc.z += (float)v[2]; acc.w += (float)v[3];
            }
        }
    } else {
        for (int base = start; base < end; base += 64) {
            int n = end - base; if (n > 64) n = 64;
            int s = 0;
            if (base + lane < end) s = sorted_src[base + lane];
            for (int j = 0; j < n; ++j) {
                int sj = __shfl(s, j);
                const f32x4_t v = *(const f32x4_t*)(x_acc + (long)sj * FDIM + lane * 4);
                acc.x += v.x; acc.y += v.y; acc.z += v.z; acc.w += v.w;
            }
        }
    }
    if (meanb) {
        float inv = 1.0f / fmaxf((float)(end - start), 1.0f);
        bf16x4_t w;
        w[0] = (__bf16)(acc.x * inv); w[1] = (__bf16)(acc.y * inv);
        w[2] = (__bf16)(acc.z * inv); w[3] = (__bf16)(acc.w * inv);
        *(bf16x4_t*)(meanb + (long)gw * FDIM + lane * 4) = w;
    } else {
        *(f32x4_t*)(summed + (long)gw * FDIM + lane * 4) = acc;
    }
}

// ---- fused GEMM: h = mean@W_l + x_tx@W_r + b_l; relu; tx_x + logits ----
__global__ __launch_bounds__(512) void gemmk(const float* __restrict__ x_tx,
                                             const __bf16* __restrict__ xtb,
                                             const float* __restrict__ summed,
                                             const __bf16* __restrict__ meanb,
                                             const int* __restrict__ row_start,
                                             const __bf16* __restrict__ WT,
                                             const float* __restrict__ b_l,
                                             const float* __restrict__ W_out,
                                             float* __restrict__ tx_out,
                                             float* __restrict__ logits) {
    __shared__ __bf16 As[128][72];   // [row][k], +8 pad
    __shared__ __bf16 Bs[256][72];   // [col][k], +8 pad

    const int m0 = blockIdx.x * 128;
    const int tid = threadIdx.x;
    const int wid = tid >> 6;
    const int lane = tid & 63;
    const int wm = wid >> 2;
    const int wn = wid & 3;
    const int lc = lane & 15;
    const int lr = lane >> 4;

    f32x4_t acc[4][4];
#pragma unroll
    for (int i = 0; i < 4; ++i)
#pragma unroll
        for (int j = 0; j < 4; ++j) acc[i][j] = (f32x4_t){0.f, 0.f, 0.f, 0.f};

    const int ar = tid >> 2;
    const int acq = tid & 3;
    const int arm = m0 + ar;
    const bool arow_ok = arm < M_TX;
    float invc = 1.0f;
    if (!meanb) {
        int idx = arow_ok ? arm : (M_TX - 1);
        int c = row_start[idx + 1] - row_start[idx];
        invc = 1.0f / fmaxf((float)c, 1.0f);
    }

    for (int kc = 0; kc < 8; ++kc) {
        __syncthreads();
        // ---- stage A tile (128 x 64 bf16) ----
        {
            const bool first = kc < 4;
            const int kb = (kc & 3) * 64;
            const __bf16* bsrc = first ? meanb : xtb;
            if (bsrc) {
                const __bf16* bb = bsrc + (long)arm * FDIM + kb + acq * 16;
                bf16x8_t v0 = bzero8(), v1 = bzero8();
                if (arow_ok) {
                    v0 = *(const bf16x8_t*)bb;
                    v1 = *(const bf16x8_t*)(bb + 8);
                }
                *(bf16x8_t*)(&As[ar][acq * 16]) = v0;
                *(bf16x8_t*)(&As[ar][acq * 16 + 8]) = v1;
            } else {
                const float sc = first ? invc : 1.0f;
                const float* base = first ? (summed + (long)arm * FDIM + kb)
                                          : (x_tx + (long)arm * FDIM + kb);
#pragma unroll
                for (int c4 = 0; c4 < 4; ++c4) {
                    int kk = acq * 16 + c4 * 4;
                    f32x4_t v = {0.f, 0.f, 0.f, 0.f};
                    if (arow_ok) v = *(const f32x4_t*)(base + kk);
                    bf16x4_t w;
                    w[0] = (__bf16)(v.x * sc);
                    w[1] = (__bf16)(v.y * sc);
                    w[2] = (__bf16)(v.z * sc);
                    w[3] = (__bf16)(v.w * sc);
                    *(bf16x4_t*)(&As[ar][kk]) = w;
                }
            }
        }
        // ---- stage B tile (256 x 64 bf16) from WT ----
#pragma unroll
        for (int i = 0; i < 4; ++i) {
            int t2 = tid + i * 512;
            int n = t2 >> 3;
            int c = t2 & 7;
            bf16x8_t v = *(const bf16x8_t*)(WT + n * KTOT + kc * 64 + c * 8);
            *(bf16x8_t*)(&Bs[n][c * 8]) = v;
        }
        __syncthreads();
        // ---- MFMA ----
        const int kfr = lr * 8;
#pragma unroll
        for (int kk = 0; kk < 2; ++kk) {
            bf16x8_t af[4], bfr[4];
#pragma unroll
            for (int f = 0; f < 4; ++f) {
                af[f] = *(const bf16x8_t*)(&As[wm * 64 + f * 16 + lc][kk * 32 + kfr]);
                bfr[f] = *(const bf16x8_t*)(&Bs[wn * 64 + f * 16 + lc][kk * 32 + kfr]);
            }
#pragma unroll
            for (int fm = 0; fm < 4; ++fm)
#pragma unroll
                for (int fn = 0; fn < 4; ++fn)
                    acc[fm][fn] = __builtin_amdgcn_mfma_f32_16x16x32_bf16(
                        af[fm], bfr[fn], acc[fm][fn], 0, 0, 0);
        }
    }

    // ---- epilogue: bias, relu, store tx_x, fused logits ----
    float wout[4], bl[4];
#pragma unroll
    for (int fn = 0; fn < 4; ++fn) {
        int col = wn * 64 + fn * 16 + lc;
        wout[fn] = W_out[col];
        bl[fn] = b_l[col];
    }
#pragma unroll
    for (int fm = 0; fm < 4; ++fm) {
        float part[4] = {0.f, 0.f, 0.f, 0.f};
#pragma unroll
        for (int fn = 0; fn < 4; ++fn) {
            int col = wn * 64 + fn * 16 + lc;
#pragma unroll
            for (int r = 0; r < 4; ++r) {
                int row = m0 + wm * 64 + fm * 16 + lr * 4 + r;
                float h = acc[fm][fn][r] + bl[fn];
                h = fmaxf(h, 0.0f);
                if (row < M_TX) tx_out[(long)row * HDIM + col] = h;
                part[r] += h * wout[fn];
            }
        }
#pragma unroll
        for (int r = 0; r < 4; ++r) {
            float p = part[r];
            p += __shfl_xor(p, 1);
            p += __shfl_xor(p, 2);
            p += __shfl_xor(p, 4);
            p += __shfl_xor(p, 8);
            int row = m0 + wm * 64 + fm * 16 + lr * 4 + r;
            if (lc == 0 && row < M_TX) unsafeAtomicAdd(logits + row, p);
        }
    }
}

extern "C" void kernel_launch(void* const* d_in, const int* in_sizes, int n_in,
                              void* d_out, int out_size, void* d_ws, size_t ws_size,
                              hipStream_t stream) {
    const float* x_tx  = (const float*)d_in[0];
    const float* x_acc = (const float*)d_in[1];
    const int* e_src   = (const int*)d_in[2];
    const int* e_dst   = (const int*)d_in[3];
    const float* W_l   = (const float*)d_in[6];
    const float* b_l   = (const float*)d_in[7];
    const float* W_r   = (const float*)d_in[8];
    const float* W_out = (const float*)d_in[12];
    const float* b_out = (const float*)d_in[13];

    float* out = (float*)d_out;
    float* logits = out;
    float* summed = out + M_TX;   // f32 accumulator (only used when meanb unavailable)

    // workspace layout (256B-aligned slots)
    char* ws = (char*)d_ws;
    size_t off = 0;
    auto alloc = [&](size_t bytes) {
        size_t o = off;
        off = (off + bytes + 255) & ~(size_t)255;
        return o;
    };
    size_t o_WT       = alloc((size_t)HDIM * KTOT * 2);       // 256 KB
    size_t o_rowstart = alloc(((size_t)M_TX + 1) * 4);        // 400 KB
    size_t o_fill     = alloc((size_t)M_TX * 4);              // 400 KB
    size_t o_sorted   = alloc((size_t)800000 * 4);            // 3.2 MB (E)
    size_t o_hist     = alloc((size_t)M_TX * 4);              // 400 KB
    size_t o_part     = alloc((size_t)SCAN_NBLK * 4);
    size_t base_end   = off;
    size_t o_xa       = alloc((size_t)N_AC * FDIM * 2);       // 25.6 MB
    size_t lvlA_end   = off;
    size_t o_mean     = alloc((size_t)M_TX * FDIM * 2);       // 51.2 MB
    size_t lvlB_end   = off;
    size_t o_xt       = alloc((size_t)M_TX * FDIM * 2);       // 51.2 MB
    size_t lvlC_end   = off;
    (void)base_end;

    __bf16* WT       = (__bf16*)(ws + o_WT);
    int* row_start   = (int*)(ws + o_rowstart);
    int* fill        = (int*)(ws + o_fill);
    int* sorted_src  = (int*)(ws + o_sorted);
    int* histp       = (int*)(ws + o_hist);
    int* partials    = (int*)(ws + o_part);

    const bool lvlA = ws_size >= lvlA_end;
    const bool lvlB = ws_size >= lvlB_end;
    const bool lvlC = ws_size >= lvlC_end;
    __bf16* xab   = lvlA ? (__bf16*)(ws + o_xa)   : nullptr;
    __bf16* meanb = lvlB ? (__bf16*)(ws + o_mean) : nullptr;
    __bf16* xtb   = lvlC ? (__bf16*)(ws + o_xt)   : nullptr;

    const int E = in_sizes[2];

    hipLaunchKernelGGL(initk2, dim3((M_TX + 255) / 256), dim3(256), 0, stream,
                       logits, histp, fill, b_out);
    hipLaunchKernelGGL(transw, dim3((FDIM * HDIM + 255) / 256), dim3(256), 0, stream,
                       W_l, W_r, WT);
    if (xab)
        hipLaunchKernelGGL(cvtk, dim3(2048), dim3(256), 0, stream,
                           x_acc, xab, N_AC * FDIM / 4);
    if (xtb)
        hipLaunchKernelGGL(cvtk, dim3(2048), dim3(256), 0, stream,
                           x_tx, xtb, M_TX * FDIM / 4);
    hipLaunchKernelGGL(histk, dim3((E + 255) / 256), dim3(256), 0, stream,
                       e_dst, histp, E);
    hipLaunchKernelGGL(scan1k, dim3(SCAN_NBLK), dim3(1024), 0, stream,
                       histp, row_start, partials);
    hipLaunchKernelGGL(scan2k, dim3(1), dim3(128), 0, stream, partials, row_start);
    hipLaunchKernelGGL(scan3k, dim3(SCAN_NBLK), dim3(1024), 0, stream,
                       row_start, partials);
    hipLaunchKernelGGL(scatterk, dim3((E + 255) / 256), dim3(256), 0, stream,
                       e_src, e_dst, row_start, fill, sorted_src, E);
    hipLaunchKernelGGL(gatherk, dim3(M_TX / 4), dim3(256), 0, stream,
                       x_acc, xab, sorted_src, row_start, summed, meanb);
    hipLaunchKernelGGL(gemmk, dim3((M_TX + 127) / 128), dim3(512), 0, stream,
                       x_tx, xtb, summed, meanb, row_start, WT, b_l, W_out,
                       out + M_TX, logits);
}

// Round 13
// 450.548 us; speedup vs baseline: 6.6210x; 1.0273x over previous
//
#include <hip/hip_runtime.h>
#include <hip/hip_bf16.h>

typedef __bf16 bf16x8_t __attribute__((ext_vector_type(8)));
typedef __bf16 bf16x4_t __attribute__((ext_vector_type(4)));
typedef float f32x4_t __attribute__((ext_vector_type(4)));

#define M_TX 100000
#define N_AC 50000
#define FDIM 256
#define HDIM 256
#define KTOT 512
#define SCAN_NBLK ((M_TX + 1023) / 1024)   // 98

__device__ inline bf16x8_t bzero8() {
    bf16x8_t v;
#pragma unroll
    for (int z = 0; z < 8; ++z) v[z] = (__bf16)0.f;
    return v;
}

// ---- fused init: logits = b_out, hist = 0, fill = 0, WT transpose ----
__global__ __launch_bounds__(256) void initk3(float* __restrict__ logits,
                                              int* __restrict__ hist,
                                              int* __restrict__ fill,
                                              const float* __restrict__ b_out,
                                              const float* __restrict__ Wl,
                                              const float* __restrict__ Wr,
                                              __bf16* __restrict__ WT) {
    int i = blockIdx.x * 256 + threadIdx.x;
    if (i < M_TX) {
        logits[i] = b_out[0];
        hist[i] = 0;
        fill[i] = 0;
    }
    if (i < FDIM * HDIM) {
        int k = i >> 8;
        int n = i & 255;
        WT[n * KTOT + k]       = (__bf16)Wl[k * HDIM + n];
        WT[n * KTOT + 256 + k] = (__bf16)Wr[k * HDIM + n];
    }
}

// ---- f32 -> bf16 bulk convert, two arrays in one launch ----
__global__ __launch_bounds__(256) void cvt2k(const float* __restrict__ s1,
                                             __bf16* __restrict__ d1, int n4_1,
                                             const float* __restrict__ s2,
                                             __bf16* __restrict__ d2, int n4_2) {
    int stride = gridDim.x * 256;
    int tot = n4_1 + n4_2;
    for (int i = blockIdx.x * 256 + threadIdx.x; i < tot; i += stride) {
        const f32x4_t* sp;
        bf16x4_t* dp;
        if (i < n4_1) { sp = (const f32x4_t*)s1 + i; dp = (bf16x4_t*)d1 + i; }
        else          { sp = (const f32x4_t*)s2 + (i - n4_1); dp = (bf16x4_t*)d2 + (i - n4_1); }
        f32x4_t v = *sp;
        bf16x4_t w;
        w[0] = (__bf16)v.x; w[1] = (__bf16)v.y;
        w[2] = (__bf16)v.z; w[3] = (__bf16)v.w;
        *dp = w;
    }
}

// ---- single-array convert (fallback when only xab fits) ----
__global__ __launch_bounds__(256) void cvtk(const float* __restrict__ src,
                                            __bf16* __restrict__ dst, int n4) {
    int stride = gridDim.x * 256;
    for (int i = blockIdx.x * 256 + threadIdx.x; i < n4; i += stride) {
        f32x4_t v = ((const f32x4_t*)src)[i];
        bf16x4_t w;
        w[0] = (__bf16)v.x; w[1] = (__bf16)v.y;
        w[2] = (__bf16)v.z; w[3] = (__bf16)v.w;
        ((bf16x4_t*)dst)[i] = w;
    }
}

// ---- histogram of dst degree ----
__global__ __launch_bounds__(256) void histk(const int* __restrict__ edst,
                                             int* __restrict__ hist, int E) {
    int e = blockIdx.x * 256 + threadIdx.x;
    if (e >= E) return;
    atomicAdd(&hist[edst[e]], 1);
}

// ---- scan pass 1 ----
__global__ __launch_bounds__(1024) void scan1k(const int* __restrict__ hist,
                                               int* __restrict__ row_start,
                                               int* __restrict__ partials) {
    __shared__ int tmp[1024];
    const int b = blockIdx.x;
    const int t = threadIdx.x;
    const int i = b * 1024 + t;
    int v = (i < M_TX) ? hist[i] : 0;
    tmp[t] = v;
    __syncthreads();
    for (int off = 1; off < 1024; off <<= 1) {
        int u = (t >= off) ? tmp[t - off] : 0;
        __syncthreads();
        tmp[t] += u;
        __syncthreads();
    }
    if (i < M_TX) row_start[i] = tmp[t] - v;
    if (t == 1023) partials[b] = tmp[1023];
}

// ---- scan pass 2 ----
__global__ __launch_bounds__(128) void scan2k(int* __restrict__ partials,
                                              int* __restrict__ row_start) {
    __shared__ int tmp[128];
    const int t = threadIdx.x;
    int v = (t < SCAN_NBLK) ? partials[t] : 0;
    tmp[t] = v;
    __syncthreads();
    for (int off = 1; off < 128; off <<= 1) {
        int u = (t >= off) ? tmp[t - off] : 0;
        __syncthreads();
        tmp[t] += u;
        __syncthreads();
    }
    if (t < SCAN_NBLK) partials[t] = tmp[t] - v;
    if (t == 127) row_start[M_TX] = tmp[127];
}

// ---- scan pass 3 ----
__global__ __launch_bounds__(1024) void scan3k(int* __restrict__ row_start,
                                               const int* __restrict__ partials) {
    const int i = blockIdx.x * 1024 + threadIdx.x;
    if (i < M_TX) row_start[i] += partials[blockIdx.x];
}

// ---- scatter edges into CSR order ----
__global__ __launch_bounds__(256) void scatterk(const int* __restrict__ esrc,
                                                const int* __restrict__ edst,
                                                const int* __restrict__ row_start,
                                                int* __restrict__ fill,
                                                int* __restrict__ sorted_src, int E) {
    int e = blockIdx.x * 256 + threadIdx.x;
    if (e >= E) return;
    int d = edst[e];
    int pos = row_start[d] + atomicAdd(&fill[d], 1);
    sorted_src[pos] = esrc[e];
}

// ---- gather-sum: one wave per dst row. bf16 fast path: 2 edges/iter, 16B loads.
__global__ __launch_bounds__(256) void gatherk(const float* __restrict__ x_acc,
                                               const __bf16* __restrict__ xab,
                                               const int* __restrict__ sorted_src,
                                               const int* __restrict__ row_start,
                                               float* __restrict__ summed,
                                               __bf16* __restrict__ meanb) {
    int gw = (blockIdx.x * 256 + threadIdx.x) >> 6;
    if (gw >= M_TX) return;
    int lane = threadIdx.x & 63;
    int start = row_start[gw];
    int end = row_start[gw + 1];
    if (xab && meanb) {
        const int l5 = lane & 31;
        const int half = lane >> 5;
        f32x4_t a0 = {0.f, 0.f, 0.f, 0.f}, a1 = {0.f, 0.f, 0.f, 0.f};
        for (int base = start; base < end; base += 64) {
            int n = end - base; if (n > 64) n = 64;
            int s = 0;
            if (base + lane < end) s = sorted_src[base + lane];
            int np = (n + 1) >> 1;
            for (int j2 = 0; j2 < np; ++j2) {
                int idx = 2 * j2 + half;
                int sj = __shfl(s, idx);
                if (idx < n) {
                    bf16x8_t v = *(const bf16x8_t*)(xab + (long)sj * FDIM + l5 * 8);
                    a0.x += (float)v[0]; a0.y += (float)v[1];
                    a0.z += (float)v[2]; a0.w += (float)v[3];
                    a1.x += (float)v[4]; a1.y += (float)v[5];
                    a1.z += (float)v[6]; a1.w += (float)v[7];
                }
            }
        }
        // combine even/odd halves (lane k + lane k+32 hold same cols)
        a0.x += __shfl_xor(a0.x, 32); a0.y += __shfl_xor(a0.y, 32);
        a0.z += __shfl_xor(a0.z, 32); a0.w += __shfl_xor(a0.w, 32);
        a1.x += __shfl_xor(a1.x, 32); a1.y += __shfl_xor(a1.y, 32);
        a1.z += __shfl_xor(a1.z, 32); a1.w += __shfl_xor(a1.w, 32);
        if (half == 0) {
            float inv = 1.0f / fmaxf((float)(end - start), 1.0f);
            bf16x8_t w;
            w[0] = (__bf16)(a0.x * inv); w[1] = (__bf16)(a0.y * inv);
            w[2] = (__bf16)(a0.z * inv); w[3] = (__bf16)(a0.w * inv);
            w[4] = (__bf16)(a1.x * inv); w[5] = (__bf16)(a1.y * inv);
            w[6] = (__bf16)(a1.z * inv); w[7] = (__bf16)(a1.w * inv);
            *(bf16x8_t*)(meanb + (long)gw * FDIM + l5 * 8) = w;
        }
        return;
    }
    // fallback paths (identical to round-8/10 verified behavior)
    f32x4_t acc = {0.f, 0.f, 0.f, 0.f};
    if (xab) {
        for (int base = start; base < end; base += 64) {
            int n = end - base; if (n > 64) n = 64;
            int s = 0;
            if (base + lane < end) s = sorted_src[base + lane];
            for (int j = 0; j < n; ++j) {
                int sj = __shfl(s, j);
                const bf16x4_t v = *(const bf16x4_t*)(xab + (long)sj * FDIM + lane * 4);
                acc.x += (float)v[0]; acc.y += (float)v[1];
                acc.z += (float)v[2]; acc.w += (float)v[3];
            }
        }
    } else {
        for (int base = start; base < end; base += 64) {
            int n = end - base; if (n > 64) n = 64;
            int s = 0;
            if (base + lane < end) s = sorted_src[base + lane];
            for (int j = 0; j < n; ++j) {
                int sj = __shfl(s, j);
                const f32x4_t v = *(const f32x4_t*)(x_acc + (long)sj * FDIM + lane * 4);
                acc.x += v.x; acc.y += v.y; acc.z += v.z; acc.w += v.w;
            }
        }
    }
    if (meanb) {
        float inv = 1.0f / fmaxf((float)(end - start), 1.0f);
        bf16x4_t w;
        w[0] = (__bf16)(acc.x * inv); w[1] = (__bf16)(acc.y * inv);
        w[2] = (__bf16)(acc.z * inv); w[3] = (__bf16)(acc.w * inv);
        *(bf16x4_t*)(meanb + (long)gw * FDIM + lane * 4) = w;
    } else {
        *(f32x4_t*)(summed + (long)gw * FDIM + lane * 4) = acc;
    }
}

// ---- fused GEMM: h = mean@W_l + x_tx@W_r + b_l; relu; tx_x + logits ----
// bf16 path: register-prefetch next K-tile (T14) to hide load latency under MFMA.
__global__ __launch_bounds__(512) void gemmk(const float* __restrict__ x_tx,
                                             const __bf16* __restrict__ xtb,
                                             const float* __restrict__ summed,
                                             const __bf16* __restrict__ meanb,
                                             const int* __restrict__ row_start,
                                             const __bf16* __restrict__ WT,
                                             const float* __restrict__ b_l,
                                             const float* __restrict__ W_out,
                                             float* __restrict__ tx_out,
                                             float* __restrict__ logits) {
    __shared__ __bf16 As[128][72];   // [row][k], +8 pad (144B rows, even bank spread)
    __shared__ __bf16 Bs[256][72];

    const int m0 = blockIdx.x * 128;
    const int tid = threadIdx.x;
    const int wid = tid >> 6;
    const int lane = tid & 63;
    const int wm = wid >> 2;
    const int wn = wid & 3;
    const int lc = lane & 15;
    const int lr = lane >> 4;

    f32x4_t acc[4][4];
#pragma unroll
    for (int i = 0; i < 4; ++i)
#pragma unroll
        for (int j = 0; j < 4; ++j) acc[i][j] = (f32x4_t){0.f, 0.f, 0.f, 0.f};

    const int ar = tid >> 2;
    const int acq = tid & 3;
    const int arm = m0 + ar;
    const bool arow_ok = arm < M_TX;

    if (meanb && xtb) {
        // ---------- bf16 fast path with register prefetch ----------
        bf16x8_t pa0, pa1, pb[4];
        {
            const __bf16* bb = meanb + (long)arm * FDIM + acq * 16;
            pa0 = bzero8(); pa1 = bzero8();
            if (arow_ok) { pa0 = *(const bf16x8_t*)bb; pa1 = *(const bf16x8_t*)(bb + 8); }
#pragma unroll
            for (int i = 0; i < 4; ++i) {
                int t2 = tid + i * 512;
                pb[i] = *(const bf16x8_t*)(WT + (t2 >> 3) * KTOT + (t2 & 7) * 8);
            }
        }
        for (int kc = 0; kc < 8; ++kc) {
            __syncthreads();   // previous tile consumed
            *(bf16x8_t*)(&As[ar][acq * 16]) = pa0;
            *(bf16x8_t*)(&As[ar][acq * 16 + 8]) = pa1;
#pragma unroll
            for (int i = 0; i < 4; ++i) {
                int t2 = tid + i * 512;
                *(bf16x8_t*)(&Bs[t2 >> 3][(t2 & 7) * 8]) = pb[i];
            }
            __syncthreads();   // tile kc visible
            if (kc < 7) {      // prefetch kc+1 — flies during MFMA below
                int kn = kc + 1;
                const __bf16* bsrc = (kn < 4) ? meanb : xtb;
                const __bf16* bb = bsrc + (long)arm * FDIM + ((kn & 3) * 64) + acq * 16;
                pa0 = bzero8(); pa1 = bzero8();
                if (arow_ok) { pa0 = *(const bf16x8_t*)bb; pa1 = *(const bf16x8_t*)(bb + 8); }
#pragma unroll
                for (int i = 0; i < 4; ++i) {
                    int t2 = tid + i * 512;
                    pb[i] = *(const bf16x8_t*)(WT + (t2 >> 3) * KTOT + kn * 64 + (t2 & 7) * 8);
                }
            }
            const int kfr = lr * 8;
#pragma unroll
            for (int kk = 0; kk < 2; ++kk) {
                bf16x8_t af[4], bfr[4];
#pragma unroll
                for (int f = 0; f < 4; ++f) {
                    af[f] = *(const bf16x8_t*)(&As[wm * 64 + f * 16 + lc][kk * 32 + kfr]);
                    bfr[f] = *(const bf16x8_t*)(&Bs[wn * 64 + f * 16 + lc][kk * 32 + kfr]);
                }
#pragma unroll
                for (int fm = 0; fm < 4; ++fm)
#pragma unroll
                    for (int fn = 0; fn < 4; ++fn)
                        acc[fm][fn] = __builtin_amdgcn_mfma_f32_16x16x32_bf16(
                            af[fm], bfr[fn], acc[fm][fn], 0, 0, 0);
            }
        }
    } else {
        // ---------- fallback (round-8 verified structure) ----------
        float invc = 1.0f;
        {
            int idx = arow_ok ? arm : (M_TX - 1);
            int c = row_start[idx + 1] - row_start[idx];
            invc = 1.0f / fmaxf((float)c, 1.0f);
        }
        for (int kc = 0; kc < 8; ++kc) {
            __syncthreads();
            {
                const bool first = kc < 4;
                const int kb = (kc & 3) * 64;
                const float sc = first ? invc : 1.0f;
                const float* base = first ? (summed + (long)arm * FDIM + kb)
                                          : (x_tx + (long)arm * FDIM + kb);
#pragma unroll
                for (int c4 = 0; c4 < 4; ++c4) {
                    int kk = acq * 16 + c4 * 4;
                    f32x4_t v = {0.f, 0.f, 0.f, 0.f};
                    if (arow_ok) v = *(const f32x4_t*)(base + kk);
                    bf16x4_t w;
                    w[0] = (__bf16)(v.x * sc);
                    w[1] = (__bf16)(v.y * sc);
                    w[2] = (__bf16)(v.z * sc);
                    w[3] = (__bf16)(v.w * sc);
                    *(bf16x4_t*)(&As[ar][kk]) = w;
                }
            }
#pragma unroll
            for (int i = 0; i < 4; ++i) {
                int t2 = tid + i * 512;
                int n = t2 >> 3;
                int c = t2 & 7;
                bf16x8_t v = *(const bf16x8_t*)(WT + n * KTOT + kc * 64 + c * 8);
                *(bf16x8_t*)(&Bs[n][c * 8]) = v;
            }
            __syncthreads();
            const int kfr = lr * 8;
#pragma unroll
            for (int kk = 0; kk < 2; ++kk) {
                bf16x8_t af[4], bfr[4];
#pragma unroll
                for (int f = 0; f < 4; ++f) {
                    af[f] = *(const bf16x8_t*)(&As[wm * 64 + f * 16 + lc][kk * 32 + kfr]);
                    bfr[f] = *(const bf16x8_t*)(&Bs[wn * 64 + f * 16 + lc][kk * 32 + kfr]);
                }
#pragma unroll
                for (int fm = 0; fm < 4; ++fm)
#pragma unroll
                    for (int fn = 0; fn < 4; ++fn)
                        acc[fm][fn] = __builtin_amdgcn_mfma_f32_16x16x32_bf16(
                            af[fm], bfr[fn], acc[fm][fn], 0, 0, 0);
            }
        }
    }

    // ---- epilogue: bias, relu, store tx_x, fused logits ----
    float wout[4], bl[4];
#pragma unroll
    for (int fn = 0; fn < 4; ++fn) {
        int col = wn * 64 + fn * 16 + lc;
        wout[fn] = W_out[col];
        bl[fn] = b_l[col];
    }
#pragma unroll
    for (int fm = 0; fm < 4; ++fm) {
        float part[4] = {0.f, 0.f, 0.f, 0.f};
#pragma unroll
        for (int fn = 0; fn < 4; ++fn) {
            int col = wn * 64 + fn * 16 + lc;
#pragma unroll
            for (int r = 0; r < 4; ++r) {
                int row = m0 + wm * 64 + fm * 16 + lr * 4 + r;
                float h = acc[fm][fn][r] + bl[fn];
                h = fmaxf(h, 0.0f);
                if (row < M_TX) tx_out[(long)row * HDIM + col] = h;
                part[r] += h * wout[fn];
            }
        }
#pragma unroll
        for (int r = 0; r < 4; ++r) {
            float p = part[r];
            p += __shfl_xor(p, 1);
            p += __shfl_xor(p, 2);
            p += __shfl_xor(p, 4);
            p += __shfl_xor(p, 8);
            int row = m0 + wm * 64 + fm * 16 + lr * 4 + r;
            if (lc == 0 && row < M_TX) unsafeAtomicAdd(logits + row, p);
        }
    }
}

extern "C" void kernel_launch(void* const* d_in, const int* in_sizes, int n_in,
                              void* d_out, int out_size, void* d_ws, size_t ws_size,
                              hipStream_t stream) {
    const float* x_tx  = (const float*)d_in[0];
    const float* x_acc = (const float*)d_in[1];
    const int* e_src   = (const int*)d_in[2];
    const int* e_dst   = (const int*)d_in[3];
    const float* W_l   = (const float*)d_in[6];
    const float* b_l   = (const float*)d_in[7];
    const float* W_r   = (const float*)d_in[8];
    const float* W_out = (const float*)d_in[12];
    const float* b_out = (const float*)d_in[13];

    float* out = (float*)d_out;
    float* logits = out;
    float* summed = out + M_TX;   // only used when meanb unavailable

    // workspace layout (256B-aligned slots)
    char* ws = (char*)d_ws;
    size_t off = 0;
    auto alloc = [&](size_t bytes) {
        size_t o = off;
        off = (off + bytes + 255) & ~(size_t)255;
        return o;
    };
    size_t o_WT       = alloc((size_t)HDIM * KTOT * 2);
    size_t o_rowstart = alloc(((size_t)M_TX + 1) * 4);
    size_t o_fill     = alloc((size_t)M_TX * 4);
    size_t o_sorted   = alloc((size_t)800000 * 4);
    size_t o_hist     = alloc((size_t)M_TX * 4);
    size_t o_part     = alloc((size_t)SCAN_NBLK * 4);
    size_t o_xa       = alloc((size_t)N_AC * FDIM * 2);
    size_t lvlA_end   = off;
    size_t o_mean     = alloc((size_t)M_TX * FDIM * 2);
    size_t lvlB_end   = off;
    size_t o_xt       = alloc((size_t)M_TX * FDIM * 2);
    size_t lvlC_end   = off;

    __bf16* WT       = (__bf16*)(ws + o_WT);
    int* row_start   = (int*)(ws + o_rowstart);
    int* fill        = (int*)(ws + o_fill);
    int* sorted_src  = (int*)(ws + o_sorted);
    int* histp       = (int*)(ws + o_hist);
    int* partials    = (int*)(ws + o_part);

    const bool lvlA = ws_size >= lvlA_end;
    const bool lvlB = ws_size >= lvlB_end;
    const bool lvlC = ws_size >= lvlC_end;
    __bf16* xab   = lvlA ? (__bf16*)(ws + o_xa)   : nullptr;
    __bf16* meanb = lvlB ? (__bf16*)(ws + o_mean) : nullptr;
    __bf16* xtb   = lvlC ? (__bf16*)(ws + o_xt)   : nullptr;

    const int E = in_sizes[2];

    hipLaunchKernelGGL(initk3, dim3((M_TX + 255) / 256), dim3(256), 0, stream,
                       logits, histp, fill, b_out, W_l, W_r, WT);
    if (xab && xtb)
        hipLaunchKernelGGL(cvt2k, dim3(2048), dim3(256), 0, stream,
                           x_acc, xab, N_AC * FDIM / 4, x_tx, xtb, M_TX * FDIM / 4);
    else if (xab)
        hipLaunchKernelGGL(cvtk, dim3(2048), dim3(256), 0, stream,
                           x_acc, xab, N_AC * FDIM / 4);
    hipLaunchKernelGGL(histk, dim3((E + 255) / 256), dim3(256), 0, stream,
                       e_dst, histp, E);
    hipLaunchKernelGGL(scan1k, dim3(SCAN_NBLK), dim3(1024), 0, stream,
                       histp, row_start, partials);
    hipLaunchKernelGGL(scan2k, dim3(1), dim3(128), 0, stream, partials, row_start);
    hipLaunchKernelGGL(scan3k, dim3(SCAN_NBLK), dim3(1024), 0, stream,
                       row_start, partials);
    hipLaunchKernelGGL(scatterk, dim3((E + 255) / 256), dim3(256), 0, stream,
                       e_src, e_dst, row_start, fill, sorted_src, E);
    hipLaunchKernelGGL(gatherk, dim3(M_TX / 4), dim3(256), 0, stream,
                       x_acc, xab, sorted_src, row_start, summed, meanb);
    hipLaunchKernelGGL(gemmk, dim3((M_TX + 127) / 128), dim3(512), 0, stream,
                       x_tx, xtb, summed, meanb, row_start, WT, b_l, W_out,
                       out + M_TX, logits);
}